// Round 2
// baseline (301.689 us; speedup 1.0000x reference)
//
#include <hip/hip_runtime.h>
#include <hip/hip_fp16.h>

#define N_    8
#define CIN   128
#define COUT  128
#define H_    128
#define W_    128
#define HO    126
#define WO    126
#define PIXPER (HO*WO)            // 15876
#define TOTPIX (N_*PIXPER)        // 127008
#define PT    128                 // pixels per block (main kernel)
#define NBLK  ((TOTPIX + PT - 1) / PT)   // 993 (last block 32 valid pixels)

typedef _Float16 f16x8 __attribute__((ext_vector_type(8)));
typedef float    f32x4 __attribute__((ext_vector_type(4)));

union U4H {
    uint4   u;
    __half2 h[4];
    f16x8   f;
};

// ---------------------------------------------------------------------------
// Kernel 1: rate map [126x126] from rates [32x32], bilinear align_corners=False
// ---------------------------------------------------------------------------
__global__ void rate_kernel(const float* __restrict__ rates, float* __restrict__ rate) {
    int t = blockIdx.x * 256 + threadIdx.x;
    if (t >= PIXPER) return;
    int ho = t / WO, wo = t - (t / WO) * WO;
    const float sc = 32.0f / 126.0f;
    float sy = fminf(fmaxf(((float)ho + 0.5f) * sc - 0.5f, 0.0f), 31.0f);
    float sx = fminf(fmaxf(((float)wo + 0.5f) * sc - 0.5f, 0.0f), 31.0f);
    int y0 = (int)sy, x0 = (int)sx;            // floor (sy,sx >= 0)
    int y1 = min(y0 + 1, 31), x1 = min(x0 + 1, 31);
    float wy = sy - (float)y0, wx = sx - (float)x0;
    float v = rates[y0 * 32 + x0] * (1.0f - wy) * (1.0f - wx)
            + rates[y0 * 32 + x1] * (1.0f - wy) * wx
            + rates[y1 * 32 + x0] * wy * (1.0f - wx)
            + rates[y1 * 32 + x1] * wy * wx;
    rate[t] = v;
}

// ---------------------------------------------------------------------------
// Kernel 2: input [N][C][H][W] fp32 -> channels-last fp16 [N][H*W][C]
// ---------------------------------------------------------------------------
__global__ void transpose_in_kernel(const float* __restrict__ in, _Float16* __restrict__ in_cl) {
    __shared__ float tile[32][33];
    int bid = blockIdx.x;
    int ct  = bid & 3;            // C/32 = 4
    int hwt = (bid >> 2) & 511;   // HW/32 = 512
    int n   = bid >> 11;          // N = 8
    int tx = threadIdx.x & 31, ty = threadIdx.x >> 5;   // (32,8)
    const float* src = in + (size_t)(n * CIN + ct * 32) * 16384 + hwt * 32;
#pragma unroll
    for (int i = 0; i < 4; ++i)
        tile[ty + i * 8][tx] = src[(size_t)(ty + i * 8) * 16384 + tx];
    __syncthreads();
    _Float16* dst = in_cl + (size_t)(n * 16384 + hwt * 32) * 128 + ct * 32;
#pragma unroll
    for (int i = 0; i < 4; ++i)
        dst[(ty + i * 8) * 128 + tx] = (_Float16)tile[tx][ty + i * 8];
}

// ---------------------------------------------------------------------------
// Kernel 3: weight [O][C][3][3] fp32 -> wt [tap][O][C] fp16 (c contiguous)
// ---------------------------------------------------------------------------
__global__ void transpose_w_kernel(const float* __restrict__ w, _Float16* __restrict__ wt) {
    int t = blockIdx.x * 256 + threadIdx.x;   // 16384 threads
    int o = t >> 7, c = t & 127;
    const float* s = w + (size_t)(o * 128 + c) * 9;
#pragma unroll
    for (int tap = 0; tap < 9; ++tap)
        wt[tap * 16384 + o * 128 + c] = (_Float16)s[tap];
}

// ---------------------------------------------------------------------------
// Main kernel: 256 threads / 4 waves, block = 128 pixels x 128 out-channels.
// Wave tile 128o x 32p via 16x16x32 f16 MFMA (8 mtiles x 2 ptiles).
// B-fragments (sampled values) are built directly in registers:
//   lane&15 -> pixel within ptile, lane>>4 -> 8-channel granule.
// W tile staged in LDS (32 KB), XOR-swizzled granules. Per-pixel tap params
// (4 offsets + 4 packed half weights) in LDS.
// Last block: pid clamped for address gen, stores guarded.
// ---------------------------------------------------------------------------
__global__ __launch_bounds__(256) void adc_main(
    const _Float16* __restrict__ in_cl, const _Float16* __restrict__ wt,
    const float* __restrict__ rate, const float* __restrict__ bias,
    float* __restrict__ out)
{
    __shared__ uint4 sW[2048];    // [o][granule ^ (o&7)]  32 KB
    __shared__ uint4 sOff[PT];    // 4 element-offsets (channel 0) per pixel
    __shared__ uint2 sWgt[PT];    // {half2(w00,w01), half2(w10,w11)}

    const int t    = threadIdx.x;
    const int lane = t & 63;
    const int wv   = t >> 6;
    const int l15  = lane & 15;
    const int quad = lane >> 4;

    // ---- per-pixel (param) identity: thread t<128 owns pixel pp ----
    const int pp  = t & 127;
    const int pid = min(blockIdx.x * PT + pp, TOTPIX - 1);   // clamp tail block
    const int n   = pid / PIXPER;
    const int rem = pid - n * PIXPER;
    const int ho  = rem / WO;
    const int wo  = rem - ho * WO;
    const float r = rate[rem];

    f32x4 acc[8][2];
    const f32x4 zero = {0.0f, 0.0f, 0.0f, 0.0f};
#pragma unroll
    for (int i = 0; i < 8; ++i) { acc[i][0] = zero; acc[i][1] = zero; }

#pragma unroll 1
    for (int tap = 0; tap < 9; ++tap) {
        // ---- stage W[tap] (o x c) into swizzled LDS ----
        const uint4* wsrc = (const uint4*)(wt + tap * 16384);
#pragma unroll
        for (int i = 0; i < 8; ++i) {
            int gi = i * 256 + t;              // granule 0..2047
            int o = gi >> 4, g = gi & 15;
            sW[(o << 4) | (g ^ (o & 7))] = wsrc[gi];
        }
        // ---- per-pixel tap params ----
        if (t < PT) {
            int kh = tap / 3, kw = tap - (tap / 3) * 3;
            float y = (float)ho + (float)kh * r;   // >= 0 always
            float x = (float)wo + (float)kw * r;   // >= 0 always
            float y0f = floorf(y), x0f = floorf(x);
            int y0 = (int)y0f, x0 = (int)x0f;
            float wy = y - y0f, wx = x - x0f;
            float vy0 = (y0 <= H_ - 1) ? 1.0f : 0.0f;
            float vy1 = (y0 <= H_ - 2) ? 1.0f : 0.0f;
            float vx0 = (x0 <= W_ - 1) ? 1.0f : 0.0f;
            float vx1 = (x0 <= W_ - 2) ? 1.0f : 0.0f;
            int yc0 = min(y0, H_ - 1), yc1 = min(y0 + 1, H_ - 1);
            int xc0 = min(x0, W_ - 1), xc1 = min(x0 + 1, W_ - 1);
            unsigned nb = ((unsigned)n << 14);
            uint4 offs;
            offs.x = (nb + (unsigned)(yc0 * W_ + xc0)) << 7;
            offs.y = (nb + (unsigned)(yc0 * W_ + xc1)) << 7;
            offs.z = (nb + (unsigned)(yc1 * W_ + xc0)) << 7;
            offs.w = (nb + (unsigned)(yc1 * W_ + xc1)) << 7;
            sOff[pp] = offs;
            float w00 = (1.0f - wy) * (1.0f - wx) * vy0 * vx0;
            float w01 = (1.0f - wy) * wx * vy0 * vx1;
            float w10 = wy * (1.0f - wx) * vy1 * vx0;
            float w11 = wy * wx * vy1 * vx1;
            __half2 wa = __floats2half2_rn(w00, w01);
            __half2 wb = __floats2half2_rn(w10, w11);
            uint2 pk;
            pk.x = __builtin_bit_cast(unsigned int, wa);
            pk.y = __builtin_bit_cast(unsigned int, wb);
            sWgt[pp] = pk;
        }
        __syncthreads();

        // ---- sample: build B-fragments in registers ----
        f16x8 bfrag[2][4];
#pragma unroll
        for (int pt = 0; pt < 2; ++pt) {
            int p = (wv << 5) + (pt << 4) + l15;
            uint4 off = sOff[p];
            uint2 wpk = sWgt[p];
            __half2 wab = __builtin_bit_cast(__half2, wpk.x);
            __half2 wcd = __builtin_bit_cast(__half2, wpk.y);
            __half2 w00v = __low2half2(wab), w01v = __high2half2(wab);
            __half2 w10v = __low2half2(wcd), w11v = __high2half2(wcd);
            int cg = quad << 3;
#pragma unroll
            for (int ks = 0; ks < 4; ++ks) {
                int cb = ks * 32 + cg;
                U4H A, B, C, D, S;
                A.u = *(const uint4*)(in_cl + off.x + cb);
                B.u = *(const uint4*)(in_cl + off.y + cb);
                C.u = *(const uint4*)(in_cl + off.z + cb);
                D.u = *(const uint4*)(in_cl + off.w + cb);
#pragma unroll
                for (int d = 0; d < 4; ++d) {
                    __half2 s = __hmul2(A.h[d], w00v);
                    s = __hfma2(B.h[d], w01v, s);
                    s = __hfma2(C.h[d], w10v, s);
                    s = __hfma2(D.h[d], w11v, s);
                    S.h[d] = s;
                }
                bfrag[pt][ks] = S.f;
            }
        }

        // ---- MFMA: D[o][p] += W[o][c] * S[c][p] ----
#pragma unroll
        for (int ks = 0; ks < 4; ++ks) {
#pragma unroll
            for (int mt = 0; mt < 8; ++mt) {
                int o = (mt << 4) | l15;
                int g = (ks << 2) | quad;
                U4H AF;
                AF.u = sW[(o << 4) | (g ^ (o & 7))];
                acc[mt][0] = __builtin_amdgcn_mfma_f32_16x16x32_f16(AF.f, bfrag[0][ks], acc[mt][0], 0, 0, 0);
                acc[mt][1] = __builtin_amdgcn_mfma_f32_16x16x32_f16(AF.f, bfrag[1][ks], acc[mt][1], 0, 0, 0);
            }
        }
        __syncthreads();
    }

    // ---- epilogue: C/D layout col=lane&15 (pixel), row=quad*4+reg (o) ----
#pragma unroll
    for (int pt = 0; pt < 2; ++pt) {
        int p        = (wv << 5) + (pt << 4) + l15;
        int pid2_raw = blockIdx.x * PT + p;
        int pid2     = min(pid2_raw, TOTPIX - 1);
        int n2   = pid2 / PIXPER;
        int rem2 = pid2 - n2 * PIXPER;
        float* obase = out + (size_t)n2 * (COUT * PIXPER) + rem2;
        if (pid2_raw < TOTPIX) {
#pragma unroll
            for (int mt = 0; mt < 8; ++mt) {
                int o0 = (mt << 4) + (quad << 2);
                float4 bs = *(const float4*)(bias + o0);   // 16B-aligned, broadcast
                f32x4 a0 = acc[mt][pt];
                obase[(size_t)(o0 + 0) * PIXPER] = a0[0] + bs.x;
                obase[(size_t)(o0 + 1) * PIXPER] = a0[1] + bs.y;
                obase[(size_t)(o0 + 2) * PIXPER] = a0[2] + bs.z;
                obase[(size_t)(o0 + 3) * PIXPER] = a0[3] + bs.w;
            }
        }
    }
}

// ---------------------------------------------------------------------------
extern "C" void kernel_launch(void* const* d_in, const int* in_sizes, int n_in,
                              void* d_out, int out_size, void* d_ws, size_t ws_size,
                              hipStream_t stream) {
    const float* inputs = (const float*)d_in[0];   // [8,128,128,128]
    const float* weight = (const float*)d_in[1];   // [128,128,3,3]
    const float* rates  = (const float*)d_in[2];   // [1,1,32,32]
    const float* bias   = (const float*)d_in[3];   // [128]
    float* out = (float*)d_out;                    // [8,128,126,126]

    char* ws = (char*)d_ws;
    _Float16* in_cl = (_Float16*)ws;                         // 33,554,432 B
    _Float16* wtp   = (_Float16*)(ws + 33554432);            //    294,912 B
    float*    rate  = (float*)(ws + 33554432 + 294912);      //     63,504 B

    rate_kernel<<<(PIXPER + 255) / 256, 256, 0, stream>>>(rates, rate);
    transpose_w_kernel<<<64, 256, 0, stream>>>(weight, wtp);
    transpose_in_kernel<<<16384, 256, 0, stream>>>(inputs, in_cl);
    adc_main<<<NBLK, 256, 0, stream>>>(in_cl, wtp, rate, bias, out);
}

// Round 3
// 252.999 us; speedup vs baseline: 1.1925x; 1.1925x over previous
//
#include <hip/hip_runtime.h>
#include <hip/hip_fp16.h>

#define N_    8
#define CIN   128
#define COUT  128
#define H_    128
#define W_    128
#define HO    126
#define WO    126
#define PIXPER (HO*WO)            // 15876
#define TOTPIX (N_*PIXPER)        // 127008
#define PT    128                 // pixels per block (main kernel)
#define BLKPERIMG 125             // ceil(15876/128): last block has 4 valid px
#define NBLK  (N_*BLKPERIMG)      // 1000; bid&7 = image = XCD (L2 locality)

typedef _Float16 f16x8 __attribute__((ext_vector_type(8)));
typedef _Float16 f16x4 __attribute__((ext_vector_type(4)));
typedef float    f32x4 __attribute__((ext_vector_type(4)));

union U4H {
    uint4   u;
    __half2 h[4];
    f16x8   f;
};

// ---------------------------------------------------------------------------
// Kernel 1: rate map [126x126] from rates [32x32], bilinear align_corners=False
// ---------------------------------------------------------------------------
__global__ void rate_kernel(const float* __restrict__ rates, float* __restrict__ rate) {
    int t = blockIdx.x * 256 + threadIdx.x;
    if (t >= PIXPER) return;
    int ho = t / WO, wo = t - (t / WO) * WO;
    const float sc = 32.0f / 126.0f;
    float sy = fminf(fmaxf(((float)ho + 0.5f) * sc - 0.5f, 0.0f), 31.0f);
    float sx = fminf(fmaxf(((float)wo + 0.5f) * sc - 0.5f, 0.0f), 31.0f);
    int y0 = (int)sy, x0 = (int)sx;
    int y1 = min(y0 + 1, 31), x1 = min(x0 + 1, 31);
    float wy = sy - (float)y0, wx = sx - (float)x0;
    float v = rates[y0 * 32 + x0] * (1.0f - wy) * (1.0f - wx)
            + rates[y0 * 32 + x1] * (1.0f - wy) * wx
            + rates[y1 * 32 + x0] * wy * (1.0f - wx)
            + rates[y1 * 32 + x1] * wy * wx;
    rate[t] = v;
}

// ---------------------------------------------------------------------------
// Kernel 2: input [N][C][H*W] fp32 -> channels-last fp16 [N][H*W][C]
// 64(c) x 64(hw) tile. Reads: 4 x float4, 256B contiguous per tile row.
// LDS float[64][65]: b128 writes conflict-free; column b32 reads 2-way (free).
// Writes: fp16 x4 (8B), 16 lanes cover 64 c = 128B contiguous.
// ---------------------------------------------------------------------------
__global__ __launch_bounds__(256) void transpose_in_kernel(
    const float* __restrict__ in, _Float16* __restrict__ in_cl)
{
    __shared__ float tile[64][65];
    int bid = blockIdx.x;
    int hwt = bid & 255;          // HW/64 = 256
    int ct  = (bid >> 8) & 1;     // C/64 = 2
    int n   = bid >> 9;           // N = 8
    int r0  = threadIdx.x >> 4;   // 0..15
    int c4  = (threadIdx.x & 15) * 4;
    const float* src = in + ((size_t)(n * CIN + ct * 64) * 16384) + hwt * 64;
#pragma unroll
    for (int k = 0; k < 4; ++k) {
        int row = r0 + k * 16;                      // c within tile
        float4 v = *(const float4*)(src + (size_t)row * 16384 + c4);
        *(float4*)&tile[row][c4] = v;               // [c][hw]
    }
    __syncthreads();
    _Float16* dst = in_cl + ((size_t)(n * 16384 + hwt * 64) * 128) + ct * 64;
#pragma unroll
    for (int k = 0; k < 4; ++k) {
        int hw = r0 + k * 16;
        f16x4 o;
        o[0] = (_Float16)tile[c4 + 0][hw];
        o[1] = (_Float16)tile[c4 + 1][hw];
        o[2] = (_Float16)tile[c4 + 2][hw];
        o[3] = (_Float16)tile[c4 + 3][hw];
        *(f16x4*)(dst + (size_t)hw * 128 + c4) = o;
    }
}

// ---------------------------------------------------------------------------
// Kernel 3: weight [O][C][3][3] fp32 -> wt [tap][O][C] fp16 (c contiguous)
// ---------------------------------------------------------------------------
__global__ void transpose_w_kernel(const float* __restrict__ w, _Float16* __restrict__ wt) {
    int t = blockIdx.x * 256 + threadIdx.x;   // 16384 threads
    int o = t >> 7, c = t & 127;
    const float* s = w + (size_t)(o * 128 + c) * 9;
#pragma unroll
    for (int tap = 0; tap < 9; ++tap)
        wt[tap * 16384 + o * 128 + c] = (_Float16)s[tap];
}

// ---------------------------------------------------------------------------
// Main kernel. Block = 128 px x 128 out-ch, 4 waves, wave tile 128o x 32p.
// bid&7 = image index -> XCD-local L2 working set (one image = 4.19 MB).
// Tap loop fully unrolled: kh/kw constants -> dead-neighbor loads/lerps
// eliminated (25/36 of gathers). W in LDS (32KB swizzled); params in LDS,
// written during W-stage phase (covered by the same barrier).
// ---------------------------------------------------------------------------
__global__ __launch_bounds__(256, 4) void adc_main(
    const _Float16* __restrict__ in_cl, const _Float16* __restrict__ wt,
    const float* __restrict__ rate, const float* __restrict__ bias,
    float* __restrict__ out)
{
    __shared__ uint4 sW[2048];    // [o][granule ^ (o&7)]  32 KB
    __shared__ uint4 sOff[PT];
    __shared__ uint2 sWgt[PT];

    const int t    = threadIdx.x;
    const int lane = t & 63;
    const int wv   = t >> 6;
    const int l15  = lane & 15;
    const int quad = lane >> 4;

    const int n     = blockIdx.x & 7;           // image == XCD slab
    const int pbase = (blockIdx.x >> 3) * PT;   // within-image pixel base

    // ---- tap-invariant per-pixel identity (waves 0-1 own param duty) ----
    const int pp = t & 127;
    int ho = 0, wo = 0;
    float r = 0.0f;
    if (t < PT) {
        int rem = min(pbase + pp, PIXPER - 1);
        ho = rem / WO;
        wo = rem - ho * WO;
        r  = rate[rem];
    }
    const unsigned nb = ((unsigned)n << 14);

    f32x4 acc[8][2];
    const f32x4 zero = {0.0f, 0.0f, 0.0f, 0.0f};
#pragma unroll
    for (int i = 0; i < 8; ++i) { acc[i][0] = zero; acc[i][1] = zero; }

#pragma unroll
    for (int tap = 0; tap < 9; ++tap) {
        const int kh = tap / 3;           // compile-time after unroll
        const int kw = tap - kh * 3;

        // ---- stage W[tap] (o x c) into swizzled LDS ----
        const uint4* wsrc = (const uint4*)(wt + tap * 16384);
#pragma unroll
        for (int i = 0; i < 8; ++i) {
            int gi = i * 256 + t;
            int o = gi >> 4, g = gi & 15;
            sW[(o << 4) | (g ^ (o & 7))] = wsrc[gi];
        }
        // ---- per-pixel tap params (CSE across taps sharing kh/kw) ----
        if (t < PT) {
            float y = (float)ho + (float)kh * r;   // exact int when kh==0
            float x = (float)wo + (float)kw * r;
            float y0f = floorf(y), x0f = floorf(x);
            int y0 = (int)y0f, x0 = (int)x0f;
            float wy = y - y0f, wx = x - x0f;
            float vy0 = (y0 <= H_ - 1) ? 1.0f : 0.0f;
            float vy1 = (y0 <= H_ - 2) ? 1.0f : 0.0f;
            float vx0 = (x0 <= W_ - 1) ? 1.0f : 0.0f;
            float vx1 = (x0 <= W_ - 2) ? 1.0f : 0.0f;
            int yc0 = min(y0, H_ - 1), yc1 = min(y0 + 1, H_ - 1);
            int xc0 = min(x0, W_ - 1), xc1 = min(x0 + 1, W_ - 1);
            uint4 offs;
            offs.x = (nb + (unsigned)(yc0 * W_ + xc0)) << 7;
            offs.y = (nb + (unsigned)(yc0 * W_ + xc1)) << 7;
            offs.z = (nb + (unsigned)(yc1 * W_ + xc0)) << 7;
            offs.w = (nb + (unsigned)(yc1 * W_ + xc1)) << 7;
            sOff[pp] = offs;
            float w00 = (1.0f - wy) * (1.0f - wx) * vy0 * vx0;
            float w01 = (1.0f - wy) * wx * vy0 * vx1;
            float w10 = wy * (1.0f - wx) * vy1 * vx0;
            float w11 = wy * wx * vy1 * vx1;
            uint2 pk;
            pk.x = __builtin_bit_cast(unsigned int, __floats2half2_rn(w00, w01));
            pk.y = __builtin_bit_cast(unsigned int, __floats2half2_rn(w10, w11));
            sWgt[pp] = pk;
        }
        __syncthreads();

        // ---- build B-fragments in registers (dead neighbors skipped) ----
        f16x8 bfrag[2][4];
#pragma unroll
        for (int pt = 0; pt < 2; ++pt) {
            int p = (wv << 5) + (pt << 4) + l15;
            uint4 off = sOff[p];
            __half2 w00v = {}, w01v = {}, w10v = {}, w11v = {};
            if (kh != 0 || kw != 0) {
                uint2 wpk = sWgt[p];
                __half2 wab = __builtin_bit_cast(__half2, wpk.x);
                __half2 wcd = __builtin_bit_cast(__half2, wpk.y);
                w00v = __low2half2(wab); w01v = __high2half2(wab);
                w10v = __low2half2(wcd); w11v = __high2half2(wcd);
            }
            int cg = quad << 3;
#pragma unroll
            for (int ks = 0; ks < 4; ++ks) {
                int cb = ks * 32 + cg;
                U4H A, B, C, D, S;
                A.u = *(const uint4*)(in_cl + off.x + cb);
                if (kw != 0) B.u = *(const uint4*)(in_cl + off.y + cb);
                if (kh != 0) C.u = *(const uint4*)(in_cl + off.z + cb);
                if (kh != 0 && kw != 0) D.u = *(const uint4*)(in_cl + off.w + cb);
                if (kh == 0 && kw == 0) {
                    S.u = A.u;                      // wy=wx=0: weight==1 exact
                } else {
#pragma unroll
                    for (int d = 0; d < 4; ++d) {
                        __half2 s = __hmul2(A.h[d], w00v);
                        if (kw != 0)             s = __hfma2(B.h[d], w01v, s);
                        if (kh != 0)             s = __hfma2(C.h[d], w10v, s);
                        if (kh != 0 && kw != 0)  s = __hfma2(D.h[d], w11v, s);
                        S.h[d] = s;
                    }
                }
                bfrag[pt][ks] = S.f;
            }
        }

        // ---- MFMA: D[o][p] += W[o][c] * S[c][p] ----
#pragma unroll
        for (int ks = 0; ks < 4; ++ks) {
#pragma unroll
            for (int mt = 0; mt < 8; ++mt) {
                int o = (mt << 4) | l15;
                int g = (ks << 2) | quad;
                U4H AF;
                AF.u = sW[(o << 4) | (g ^ (o & 7))];
                acc[mt][0] = __builtin_amdgcn_mfma_f32_16x16x32_f16(AF.f, bfrag[0][ks], acc[mt][0], 0, 0, 0);
                acc[mt][1] = __builtin_amdgcn_mfma_f32_16x16x32_f16(AF.f, bfrag[1][ks], acc[mt][1], 0, 0, 0);
            }
        }
        __syncthreads();
    }

    // ---- epilogue: C/D layout col=lane&15 (pixel), row=quad*4+reg (o) ----
#pragma unroll
    for (int pt = 0; pt < 2; ++pt) {
        int p    = (wv << 5) + (pt << 4) + l15;
        int prel = pbase + p;                       // within-image pixel
        int rem2 = min(prel, PIXPER - 1);
        float* obase = out + (size_t)n * (COUT * PIXPER) + rem2;
        if (prel < PIXPER) {
#pragma unroll
            for (int mt = 0; mt < 8; ++mt) {
                int o0 = (mt << 4) + (quad << 2);
                float4 bs = *(const float4*)(bias + o0);
                f32x4 a0 = acc[mt][pt];
                obase[(size_t)(o0 + 0) * PIXPER] = a0[0] + bs.x;
                obase[(size_t)(o0 + 1) * PIXPER] = a0[1] + bs.y;
                obase[(size_t)(o0 + 2) * PIXPER] = a0[2] + bs.z;
                obase[(size_t)(o0 + 3) * PIXPER] = a0[3] + bs.w;
            }
        }
    }
}

// ---------------------------------------------------------------------------
extern "C" void kernel_launch(void* const* d_in, const int* in_sizes, int n_in,
                              void* d_out, int out_size, void* d_ws, size_t ws_size,
                              hipStream_t stream) {
    const float* inputs = (const float*)d_in[0];   // [8,128,128,128]
    const float* weight = (const float*)d_in[1];   // [128,128,3,3]
    const float* rates  = (const float*)d_in[2];   // [1,1,32,32]
    const float* bias   = (const float*)d_in[3];   // [128]
    float* out = (float*)d_out;                    // [8,128,126,126]

    char* ws = (char*)d_ws;
    _Float16* in_cl = (_Float16*)ws;                         // 33,554,432 B
    _Float16* wtp   = (_Float16*)(ws + 33554432);            //    294,912 B
    float*    rate  = (float*)(ws + 33554432 + 294912);      //     63,504 B

    rate_kernel<<<(PIXPER + 255) / 256, 256, 0, stream>>>(rates, rate);
    transpose_w_kernel<<<64, 256, 0, stream>>>(weight, wtp);
    transpose_in_kernel<<<4096, 256, 0, stream>>>(inputs, in_cl);
    adc_main<<<NBLK, 256, 0, stream>>>(in_cl, wtp, rate, bias, out);
}